// Round 2
// baseline (1872.163 us; speedup 1.0000x reference)
//
#include <hip/hip_runtime.h>
#include <math.h>

#define CIN  3
#define COUT 24
#define KS   3
#define DIN  16
#define HIN  128
#define HOUT 126
#define DOUT 14

__global__ __launch_bounds__(128) void conv3d_min_softmax(
    const float* __restrict__ x,
    const float* __restrict__ wgt,
    const float* __restrict__ bias,
    float* __restrict__ out)
{
    const int tid = threadIdx.x;
    const int h  = blockIdx.x;   // 0..125
    const int b  = blockIdx.y;   // 0..15
    const int wc = tid;          // 0..127, columns 126/127 idle
    if (wc >= HOUT) return;

    const float* xb = x + (size_t)b * (CIN * DIN * HIN * HIN);

    float m[COUT];
    #pragma unroll
    for (int c = 0; c < COUT; ++c) m[c] = 3.4e38f;

    #pragma unroll 1   // keep body ~16KB, inside I$; also bounds SGPR pressure
    for (int dp = 0; dp < DOUT; ++dp) {
        // Opaque copy of the weight pointer: prevents LICM from hoisting all
        // 24*81 weight loads out of the dp loop (would force a huge spill).
        // Re-loads per dp hit the scalar cache (weights are only 7.6 KB).
        const float* wbase = wgt;
        asm volatile("" : "+s"(wbase));

        // load the 3x3x3x3 input patch for this output pixel & depth slice
        float px[81];
        #pragma unroll
        for (int ci = 0; ci < CIN; ++ci) {
            #pragma unroll
            for (int kd = 0; kd < KS; ++kd) {
                const float* xrow0 =
                    xb + ((size_t)(ci * DIN + dp + kd) * HIN + h) * HIN + wc;
                #pragma unroll
                for (int kh = 0; kh < KS; ++kh) {
                    #pragma unroll
                    for (int kw = 0; kw < KS; ++kw) {
                        px[((ci * KS + kd) * KS + kh) * KS + kw] =
                            xrow0[kh * HIN + kw];
                    }
                }
            }
        }

        // All 24 channels against this patch. Weight addresses are
        // wave-uniform + compile-time constant -> compiler emits s_load
        // batches (SMEM pipe, SGPR operands) -> no LDS, no VALU load cost.
        #pragma unroll
        for (int co = 0; co < COUT; ++co) {
            const float* wp = wbase + co * 81;
            float s0 = 0.0f, s1 = 0.0f, s2 = 0.0f;  // 3-way split dep chain
            #pragma unroll
            for (int t = 0; t < 27; ++t) {
                s0 = fmaf(px[3 * t + 0], wp[3 * t + 0], s0);
                s1 = fmaf(px[3 * t + 1], wp[3 * t + 1], s1);
                s2 = fmaf(px[3 * t + 2], wp[3 * t + 2], s2);
            }
            float s = (s0 + s1) + s2;
            m[co] = fminf(m[co], s);
        }
    }

    // bias (depth-invariant, commutes with min) + softmax over channels
    float mx = -3.4e38f;
    #pragma unroll
    for (int c = 0; c < COUT; ++c) {
        m[c] += bias[c];                 // uniform scalar load
        mx = fmaxf(mx, m[c]);
    }
    float sum = 0.0f;
    #pragma unroll
    for (int c = 0; c < COUT; ++c) {
        m[c] = __expf(m[c] - mx);
        sum += m[c];
    }
    const float r = 1.0f / sum;

    float* ob = out + ((size_t)b * COUT * HOUT + h) * HOUT + wc;
    #pragma unroll
    for (int c = 0; c < COUT; ++c) {
        ob[(size_t)c * HOUT * HOUT] = m[c] * r;
    }
}

extern "C" void kernel_launch(void* const* d_in, const int* in_sizes, int n_in,
                              void* d_out, int out_size, void* d_ws, size_t ws_size,
                              hipStream_t stream) {
    const float* x    = (const float*)d_in[0];
    const float* wgt  = (const float*)d_in[1];
    const float* bias = (const float*)d_in[2];
    float* out        = (float*)d_out;

    dim3 grid(HOUT, 16);   // (h, b)
    dim3 block(128);
    conv3d_min_softmax<<<grid, block, 0, stream>>>(x, wgt, bias, out);
}

// Round 3
// 215.156 us; speedup vs baseline: 8.7014x; 8.7014x over previous
//
#include <hip/hip_runtime.h>
#include <math.h>

#define CIN  3
#define COUT 24
#define KS   3
#define DIN  16
#define HIN  128
#define WIN  128
#define HOUT 126
#define DOUT 14

// ---------------- Phase 1: conv3d + min over depth (pre-bias) ----------------
// grid = 3 co-groups x 16 batches x 32 h-tiles = 1536 one-wave blocks.
// Lane = 16 w-chunks x 4 h-rows; each lane computes acc[8co][8pix].
// Weights transposed in LDS: wT[t][co] so one ds_read_b128 = 4 co-weights.
__global__ __launch_bounds__(64) void conv_min_kernel(
    const float* __restrict__ x,
    const float* __restrict__ wgt,
    float* __restrict__ y)        // y = d_out, [16][24][126][126], pre-bias conv-min
{
    __shared__ float wT[81 * 24];   // [t][co], 7776 B

    const int tid = threadIdx.x;

    // stage transposed weights: wT[t*24+co] = wgt[co*81+t]
    for (int idx = tid; idx < 81 * 24; idx += 64) {
        int t  = idx / 24;
        int co = idx - t * 24;
        wT[idx] = wgt[co * 81 + t];
    }
    __syncthreads();

    const int g  = blockIdx.x % 3;            // co-group (co = g*8 .. g*8+7)
    int tmp      = blockIdx.x / 3;
    const int b  = tmp & 15;
    const int ht = tmp >> 4;                  // 0..31
    const int h0 = ht * 4;

    const int chunk = tid & 15;               // w-chunk: pixels w0..w0+7
    const int hh    = tid >> 4;               // 0..3
    const int hout  = h0 + hh;                // output row, valid < 126
    const bool hvalid = hout < HOUT;
    const int w0    = chunk * 8;

    // lane-row base offset within a (ci,d) slice; clamp invalid rows to row 0
    const int row_off = (hvalid ? hout : 0) * WIN + w0;
    const float* xb = x + (size_t)b * (CIN * DIN * HIN * WIN);

    // halo float2: chunk 15 would read w=128,129 (OOB) -> re-read +4 (dup, masked)
    const int halo_off = (chunk == 15) ? 4 : 8;

    float m[8][8];
    #pragma unroll
    for (int c = 0; c < 8; ++c)
        #pragma unroll
        for (int p = 0; p < 8; ++p) m[c][p] = 3.4e38f;

    #pragma unroll 1
    for (int dp = 0; dp < DOUT; ++dp) {
        float acc[8][8];
        #pragma unroll
        for (int c = 0; c < 8; ++c)
            #pragma unroll
            for (int p = 0; p < 8; ++p) acc[c][p] = 0.0f;

        #pragma unroll 1
        for (int ci = 0; ci < CIN; ++ci) {
            #pragma unroll 1
            for (int kd = 0; kd < KS; ++kd) {
                const float* xsl =
                    xb + (size_t)(ci * DIN + dp + kd) * (HIN * WIN) + row_off;
                #pragma unroll
                for (int kh = 0; kh < KS; ++kh) {
                    const float* xr = xsl + kh * WIN;
                    // 10 px values: 8 pixels + 2 halo
                    float px[10];
                    *(float4*)&px[0] = *(const float4*)(xr);
                    *(float4*)&px[4] = *(const float4*)(xr + 4);
                    float2 h2 = *(const float2*)(xr + halo_off);
                    px[8] = h2.x; px[9] = h2.y;

                    const float* wr = &wT[((ci * 3 + kd) * 3 + kh) * 3 * 24 + g * 8];
                    #pragma unroll
                    for (int kw = 0; kw < 3; ++kw) {
                        float wv[8];
                        *(float4*)&wv[0] = *(const float4*)(wr + kw * 24);
                        *(float4*)&wv[4] = *(const float4*)(wr + kw * 24 + 4);
                        #pragma unroll
                        for (int c = 0; c < 8; ++c)
                            #pragma unroll
                            for (int p = 0; p < 8; ++p)
                                acc[c][p] = fmaf(wv[c], px[p + kw], acc[c][p]);
                    }
                }
            }
        }
        #pragma unroll
        for (int c = 0; c < 8; ++c)
            #pragma unroll
            for (int p = 0; p < 8; ++p)
                m[c][p] = fminf(m[c][p], acc[c][p]);
    }

    // store conv-min (pre-bias); invalid rows/cols masked
    float* yb = y + ((size_t)b * COUT + g * 8) * (HOUT * HOUT)
                  + (size_t)hout * HOUT + w0;
    #pragma unroll
    for (int c = 0; c < 8; ++c) {
        #pragma unroll
        for (int p = 0; p < 8; ++p) {
            if (hvalid && (w0 + p) < HOUT)
                yb[(size_t)c * (HOUT * HOUT) + p] = m[c][p];
        }
    }
}

// ---------------- Phase 2: bias + softmax over channels, in place ----------------
__global__ __launch_bounds__(128) void bias_softmax_kernel(
    const float* __restrict__ bias,
    float* __restrict__ y)
{
    const int w = threadIdx.x;
    if (w >= HOUT) return;
    const int h = blockIdx.x;
    const int b = blockIdx.y;

    float* p = y + (size_t)b * COUT * (HOUT * HOUT) + (size_t)h * HOUT + w;

    float v[COUT];
    float mx = -3.4e38f;
    #pragma unroll
    for (int c = 0; c < COUT; ++c) {
        v[c] = p[(size_t)c * (HOUT * HOUT)] + bias[c];
        mx = fmaxf(mx, v[c]);
    }
    float sum = 0.0f;
    #pragma unroll
    for (int c = 0; c < COUT; ++c) {
        v[c] = __expf(v[c] - mx);
        sum += v[c];
    }
    const float r = 1.0f / sum;
    #pragma unroll
    for (int c = 0; c < COUT; ++c) {
        p[(size_t)c * (HOUT * HOUT)] = v[c] * r;
    }
}

extern "C" void kernel_launch(void* const* d_in, const int* in_sizes, int n_in,
                              void* d_out, int out_size, void* d_ws, size_t ws_size,
                              hipStream_t stream) {
    const float* x    = (const float*)d_in[0];
    const float* wgt  = (const float*)d_in[1];
    const float* bias = (const float*)d_in[2];
    float* out        = (float*)d_out;

    conv_min_kernel<<<dim3(3 * 16 * 32), dim3(64), 0, stream>>>(x, wgt, out);
    bias_softmax_kernel<<<dim3(HOUT, 16), dim3(128), 0, stream>>>(bias, out);
}